// Round 10
// baseline (384.022 us; speedup 1.0000x reference)
//
#include <hip/hip_runtime.h>
#include <hip/hip_bf16.h>

#define NP 16384   // H*W
#define NB 4

typedef __hip_bfloat16 bf16;
typedef unsigned short u16;
typedef unsigned short us8 __attribute__((ext_vector_type(8)));
typedef unsigned short us4 __attribute__((ext_vector_type(4)));
typedef short ss8 __attribute__((ext_vector_type(8)));
typedef float f32x4 __attribute__((ext_vector_type(4)));
__device__ __forceinline__ float bf2f(const bf16 v) { return __bfloat162float(v); }
__device__ __forceinline__ bf16 f2bf(float v) { return __float2bfloat16(v); }
__device__ __forceinline__ float bfu(u16 h) {
  return __uint_as_float(((unsigned)h) << 16);
}
__device__ __forceinline__ u16 fbu(float v) {
  bf16 b = f2bf(v);
  return *(u16*)&b;
}

// Inputs/outputs fp32 (reference dtype). Internal tensors bf16, math fp32.
// 7-dispatch pipeline: pool_conv(+stats partials) -> stats_p2 -> conv+gram ->
// transpose -> av (flash) -> merge+gram_reduce -> final.

// ---------------------------------------------------------------------------
// K1: maxpool2x2(fb) + conv1x1 on MFMA + BN-stats partials. 1024 blocks =
// b(4) x 64-px tile(256). Stats reduced from fp32 acc (pre-rounding):
// per-oc sum/sumsq via shfl_xor(16/32) + 2KB LDS -> PS[blk][128].
// ---------------------------------------------------------------------------
__global__ __launch_bounds__(256, 4) void k_pool_conv(
    const float* __restrict__ fb, const float* __restrict__ wconv,
    const float* __restrict__ bconv, bf16* __restrict__ Y,
    float* __restrict__ PS) {
  __shared__ __align__(16) u16 Xs[64 * 64];               // [px][c], swizzled
  __shared__ __align__(16) u16 wHi[64 * 64], wLo[64 * 64];  // [oc][c], swz
  __shared__ float bS[64];
  __shared__ float redS[256], redSS[256];   // [wave][oc]
  int tid = threadIdx.x;
  int b = blockIdx.x >> 8, tile = blockIdx.x & 255;
  int n0 = tile * 64;
  int h = n0 >> 7, w0 = n0 & 127;
  for (int i = tid; i < 4096; i += 256) {
    int oc = i >> 6;
    float wv = wconv[i];
    u16 hb = fbu(wv);
    u16 lb = fbu(wv - bfu(hb));
    int idx = i ^ ((oc & 7) << 3);
    wHi[idx] = hb;
    wLo[idx] = lb;
  }
  if (tid < 64) bS[tid] = bconv[tid];
  for (int i2 = tid; i2 < 2048; i2 += 256) {
    int c = i2 >> 5, pp = i2 & 31;
    const float* r0 =
        fb + ((size_t)((b * 64 + c) * 256 + 2 * h)) * 256 + 2 * w0 + 4 * pp;
    float4 v0 = *(const float4*)r0;
    float4 v1 = *(const float4*)(r0 + 256);
    int px = 2 * pp;
    float a0 = fmaxf(fmaxf(v0.x, v0.y), fmaxf(v1.x, v1.y));
    float a1 = fmaxf(fmaxf(v0.z, v0.w), fmaxf(v1.z, v1.w));
    Xs[(px * 64 + c) ^ ((((px & 7) ^ ((px >> 3) & 7))) << 3)] = fbu(a0);
    px++;
    Xs[(px * 64 + c) ^ ((((px & 7) ^ ((px >> 3) & 7))) << 3)] = fbu(a1);
  }
  __syncthreads();
  int lane = tid & 63, wvid = tid >> 6;
  int il = lane & 15, gq = lane >> 4;
  int pxb = wvid * 16;               // wave owns 16 px
  ss8 afr[2];
#pragma unroll
  for (int ks = 0; ks < 2; ++ks) {
    int px = pxb + il;
    int idx =
        (px * 64 + ks * 32 + gq * 8) ^ ((((px & 7) ^ ((px >> 3) & 7))) << 3);
    afr[ks] = *(const ss8*)&Xs[idx];
  }
#pragma unroll
  for (int oct = 0; oct < 4; ++oct) {
    int oc = oct * 16 + il;          // B-col = out-channel
    ss8 wh[2], wl[2];
#pragma unroll
    for (int ks = 0; ks < 2; ++ks) {
      int idx = (oc * 64 + ks * 32 + gq * 8) ^ ((oc & 7) << 3);
      wh[ks] = *(const ss8*)&wHi[idx];
      wl[ks] = *(const ss8*)&wLo[idx];
    }
    float bv = bS[oc];
    f32x4 acc = {bv, bv, bv, bv};
#pragma unroll
    for (int ks = 0; ks < 2; ++ks) {
      acc = __builtin_amdgcn_mfma_f32_16x16x32_bf16(afr[ks], wh[ks], acc, 0, 0, 0);
      acc = __builtin_amdgcn_mfma_f32_16x16x32_bf16(afr[ks], wl[ks], acc, 0, 0, 0);
    }
    int px0 = pxb + gq * 4;          // D rows = 4 consecutive px
    us4 ov;
#pragma unroll
    for (int r = 0; r < 4; ++r) ov[r] = fbu(acc[r]);
    *(us4*)(Y + (size_t)(b * 64 + oc) * NP + n0 + px0) = ov;
    // BN stats partials (fp32, pre-rounding)
    float s_oc = (acc[0] + acc[1]) + (acc[2] + acc[3]);
    float ss_oc = fmaf(acc[0], acc[0],
                  fmaf(acc[1], acc[1], fmaf(acc[2], acc[2], acc[3] * acc[3])));
    s_oc += __shfl_xor(s_oc, 16, 64);
    s_oc += __shfl_xor(s_oc, 32, 64);
    ss_oc += __shfl_xor(ss_oc, 16, 64);
    ss_oc += __shfl_xor(ss_oc, 32, 64);
    if (gq == 0) { redS[wvid * 64 + oc] = s_oc; redSS[wvid * 64 + oc] = ss_oc; }
  }
  __syncthreads();
  if (tid < 128) {
    int st = tid >> 6, oc = tid & 63;
    const float* rr = st ? redSS : redS;
    PS[(size_t)blockIdx.x * 128 + tid] =
        (rr[oc] + rr[64 + oc]) + (rr[128 + oc] + rr[192 + oc]);
  }
}

// ---------------------------------------------------------------------------
// K2: reduce 1024x128 stats partials; BN scale/shift + scalar header.
// ---------------------------------------------------------------------------
__global__ __launch_bounds__(256) void k_stats_p2(
    const float* __restrict__ PS, const float* __restrict__ bng,
    const float* __restrict__ bnb, float* __restrict__ SCALE,
    float* __restrict__ SHIFT, const float* xg, const float* fg,
    const float* pg, const float* pg2, const float* cg,
    float* __restrict__ HDR) {
  int t = threadIdx.x;
  __shared__ float sh[256];
  int s = t & 127, half = t >> 7;
  float a = 0.f;
  for (int blk = half * 512; blk < half * 512 + 512; ++blk)
    a += PS[(size_t)blk * 128 + s];
  sh[t] = a;
  __syncthreads();
  if (t < 128) sh[t] = sh[t] + sh[128 + t];
  __syncthreads();
  if (t < 64) {
    float ssum = sh[t], sqs = sh[64 + t];
    const float inv = 1.0f / (NB * NP);
    float mu = ssum * inv;
    float var = sqs * inv - mu * mu;
    float r = rsqrtf(var + 1e-5f);
    float sc = r * bng[t];
    SCALE[t] = sc;
    SHIFT[t] = bnb[t] - mu * sc;
    if (t == 0) {
      float vpg = pg[0];
      HDR[1] = vpg * xg[0];
      HDR[2] = pg2[0] * fg[0];
      HDR[3] = 2.0f + vpg;
      HDR[4] = pg2[0];
      HDR[5] = cg[0];
    }
  }
}

// ---------------------------------------------------------------------------
// K3: fused dispatch: blocks [0,1024) = QKV conv1x1 on MFMA (both modules,
// weights hi+lo bf16); blocks [1024,1536) = Gram partials of y=BN(Y).
// Shared memory unioned via one char buffer (37.2 KB).
// ---------------------------------------------------------------------------
__global__ __launch_bounds__(256, 4) void k_conv_gram(
    const float* __restrict__ xin, const bf16* __restrict__ Yin,
    const float* __restrict__ SCALE, const float* __restrict__ SHIFT,
    const float* __restrict__ qw0, const float* __restrict__ qb0,
    const float* __restrict__ kw0, const float* __restrict__ kb0,
    const float* __restrict__ vw0, const float* __restrict__ vb0,
    const float* __restrict__ qw1, const float* __restrict__ qb1,
    const float* __restrict__ kw1, const float* __restrict__ kb1,
    const float* __restrict__ vw1, const float* __restrict__ vb1,
    bf16* __restrict__ QK, bf16* __restrict__ V, float* __restrict__ GP) {
  __shared__ __align__(16) char SMEM[37248];
  int tid = threadIdx.x;
  if (blockIdx.x < 1024) {
    u16* Xs = (u16*)SMEM;                    // 16384 B [px][c], swizzled
    u16* wHi = (u16*)(SMEM + 16384);         // 10240 B [oc][c], swz
    u16* wLo = (u16*)(SMEM + 26624);         // 10240 B
    float* bS = (float*)(SMEM + 36864);      // 320 B
    int m = blockIdx.x >> 9;
    int b = (blockIdx.x >> 7) & 3;
    int tile = blockIdx.x & 127;
    int n0 = tile * 128;
    const float* qw = m ? qw1 : qw0;
    const float* qb = m ? qb1 : qb0;
    const float* kw = m ? kw1 : kw0;
    const float* kb = m ? kb1 : kb0;
    const float* vw = m ? vw1 : vw0;
    const float* vb = m ? vb1 : vb0;
    for (int i = tid; i < 5120; i += 256) {
      int oc = i >> 6, c = i & 63;
      float w;
      if (oc < 8) w = qw[oc * 64 + c];
      else if (oc < 16) w = kw[(oc - 8) * 64 + c];
      else w = vw[(oc - 16) * 64 + c];
      u16 hb = fbu(w);
      u16 lb = fbu(w - bfu(hb));
      int idx = (oc * 64 + c) ^ ((oc & 7) << 3);
      wHi[idx] = hb;
      wLo[idx] = lb;
    }
    if (tid < 80)
      bS[tid] = (tid < 8) ? qb[tid] : (tid < 16) ? kb[tid - 8] : vb[tid - 16];
    if (m) {
      for (int i2 = tid; i2 < 1024; i2 += 256) {
        int c = i2 >> 4, vj = i2 & 15;
        us8 v = *(const us8*)(Yin + (size_t)(b * 64 + c) * NP + n0 + vj * 8);
        float sc = SCALE[c], sh = SHIFT[c];
#pragma unroll
        for (int e = 0; e < 8; ++e) {
          int px = vj * 8 + e;
          float f = fmaxf(fmaf(bfu(v[e]), sc, sh), 0.f);
          Xs[(px * 64 + c) ^ ((((px & 7) ^ ((px >> 3) & 7))) << 3)] = fbu(f);
        }
      }
    } else {
      for (int i2 = tid; i2 < 2048; i2 += 256) {
        int c = i2 >> 5, vj = i2 & 31;
        float4 v = *(const float4*)(xin + (size_t)(b * 64 + c) * NP + n0 + vj * 4);
        float vv[4] = {v.x, v.y, v.z, v.w};
#pragma unroll
        for (int r = 0; r < 4; ++r) {
          int px = vj * 4 + r;
          Xs[(px * 64 + c) ^ ((((px & 7) ^ ((px >> 3) & 7))) << 3)] = fbu(vv[r]);
        }
      }
    }
    __syncthreads();
    int lane = tid & 63, wvid = tid >> 6;
    int il = lane & 15, gq = lane >> 4;
    int pxb = wvid * 32;
    ss8 afr[2][2];
#pragma unroll
    for (int sub = 0; sub < 2; ++sub)
#pragma unroll
      for (int ks = 0; ks < 2; ++ks) {
        int px = pxb + sub * 16 + il;
        int idx =
            (px * 64 + ks * 32 + gq * 8) ^ ((((px & 7) ^ ((px >> 3) & 7))) << 3);
        afr[sub][ks] = *(const ss8*)&Xs[idx];
      }
#pragma unroll
    for (int oct = 0; oct < 5; ++oct) {
      int oc = oct * 16 + il;   // B-col = out-channel
      ss8 wh[2], wl[2];
#pragma unroll
      for (int ks = 0; ks < 2; ++ks) {
        int idx = (oc * 64 + ks * 32 + gq * 8) ^ ((oc & 7) << 3);
        wh[ks] = *(const ss8*)&wHi[idx];
        wl[ks] = *(const ss8*)&wLo[idx];
      }
      float bv = bS[oc];
      bf16* dst;
      size_t basep;
      if (oc < 8) { dst = QK; basep = (size_t)(((m * 2 + 0) * 4 + b) * 8 + oc) * NP; }
      else if (oc < 16) { dst = QK; basep = (size_t)(((m * 2 + 1) * 4 + b) * 8 + (oc - 8)) * NP; }
      else { dst = V; basep = (size_t)((m * 4 + b) * 64 + (oc - 16)) * NP; }
#pragma unroll
      for (int sub = 0; sub < 2; ++sub) {
        f32x4 acc = {bv, bv, bv, bv};
#pragma unroll
        for (int ks = 0; ks < 2; ++ks) {
          acc = __builtin_amdgcn_mfma_f32_16x16x32_bf16(afr[sub][ks], wh[ks], acc, 0, 0, 0);
          acc = __builtin_amdgcn_mfma_f32_16x16x32_bf16(afr[sub][ks], wl[ks], acc, 0, 0, 0);
        }
        int px0 = pxb + sub * 16 + gq * 4;   // D rows = 4 consecutive px
        us4 ov;
#pragma unroll
        for (int r = 0; r < 4; ++r) ov[r] = fbu(acc[r]);
        *(us4*)(dst + basep + n0 + px0) = ov;
      }
    }
  } else {
    // ---- Gram partials: bid = b x ch x t ----
    float* fs = (float*)SMEM;   // 64*129 floats = 33024 B
    int bid = blockIdx.x - 1024;
    int b = bid >> 7, ch = (bid >> 2) & 31, t = bid & 3;
    int cg = tid >> 4, dg = tid & 15;
    float acc[4][4];
#pragma unroll
    for (int i = 0; i < 4; ++i)
#pragma unroll
      for (int jx = 0; jx < 4; ++jx) acc[i][jx] = 0.f;
    const bf16* yb = Yin + (size_t)b * 64 * NP + ch * 512;
    for (int idx = tid; idx < 8192; idx += 256) {
      int c = idx >> 7, j = idx & 127;
      float v = fmaf(bf2f(yb[(size_t)c * NP + t * 128 + j]), SCALE[c], SHIFT[c]);
      fs[c * 129 + j] = fmaxf(v, 0.f);
    }
    __syncthreads();
    for (int j = 0; j < 128; ++j) {
      float a[4], d[4];
#pragma unroll
      for (int i = 0; i < 4; ++i) a[i] = fs[(cg * 4 + i) * 129 + j];
#pragma unroll
      for (int i = 0; i < 4; ++i) d[i] = fs[(dg * 4 + i) * 129 + j];
#pragma unroll
      for (int i = 0; i < 4; ++i)
#pragma unroll
        for (int jx = 0; jx < 4; ++jx) acc[i][jx] = fmaf(a[i], d[jx], acc[i][jx]);
    }
    float* gp = GP + ((size_t)(b * 128) + ch * 4 + t) * 4096;
#pragma unroll
    for (int i = 0; i < 4; ++i)
#pragma unroll
      for (int jx = 0; jx < 4; ++jx)
        gp[(cg * 4 + i) * 64 + dg * 4 + jx] = acc[i][jx];
  }
}

// ---------------------------------------------------------------------------
// K4: 128x128 bf16 plane transpose over two tensor pairs in one dispatch.
// ---------------------------------------------------------------------------
__global__ __launch_bounds__(256) void k_transpose2(
    const u16* __restrict__ inA, u16* __restrict__ outA,
    const u16* __restrict__ inB, u16* __restrict__ outB, int nA) {
  int tileId = blockIdx.x & 15;
  int plane = blockIdx.x >> 4;
  const u16* ip;
  u16* op;
  if (plane < nA) {
    ip = inA + (size_t)plane * NP;
    op = outA + (size_t)plane * NP;
  } else {
    ip = inB + (size_t)(plane - nA) * NP;
    op = outB + (size_t)(plane - nA) * NP;
  }
  int th = tileId >> 2, tw = tileId & 3;
  __shared__ u16 t[32][33];
  int lx = threadIdx.x & 31, ly = threadIdx.x >> 5;
  for (int i = 0; i < 32; i += 8)
    t[ly + i][lx] = ip[(size_t)(th * 32 + ly + i) * 128 + tw * 32 + lx];
  __syncthreads();
  for (int i = 0; i < 32; i += 8)
    op[(size_t)(tw * 32 + ly + i) * 128 + th * 32 + lx] = t[lx][ly + i];
}

// ---------------------------------------------------------------------------
// K5: out_w + out_h, both modules, on MFMA, flash-style. 2048 blocks =
// (b,h) x mode x m; 256 thr. Both outputs bf16 now (OWb and OHT).
// ---------------------------------------------------------------------------
__global__ __launch_bounds__(256, 4) void k_av(
    const bf16* __restrict__ QK, const bf16* __restrict__ QKT,
    const bf16* __restrict__ V, const bf16* __restrict__ VT,
    float* __restrict__ MWp, float* __restrict__ LWp,
    float* __restrict__ MHp, float* __restrict__ LHp,
    bf16* __restrict__ OWb, bf16* __restrict__ OHT) {
  int blk = blockIdx.x;
  int m = blk & 1, mode = (blk >> 1) & 1;
  int bid = blk >> 2;
  int b = bid >> 7, h = bid & 127;
  const bf16* qkbase = mode ? QKT : QK;
  const bf16* Qp = qkbase + (size_t)(((m * 2 + 0) * 4 + b) * 8) * NP;
  const bf16* Kp = qkbase + (size_t)(((m * 2 + 1) * 4 + b) * 8) * NP;
  const bf16* Vp = (mode ? VT : V) + (size_t)((m * 4 + b) * 64) * NP;
  __shared__ __align__(16) u16 qT[128 * 8];    // [p(j)][c]
  __shared__ __align__(16) u16 kT[128 * 8];    // [p(j)][c]
  __shared__ __align__(16) u16 Vs[64 * 136];   // [c][j], pad 136
  int tid = threadIdx.x;
  {  // q (tid<128) / k (tid>=128): 1024 u16 each, one us8 load per thread
    int c = (tid >> 4) & 7, vj = tid & 15;
    const bf16* src = (tid < 128) ? Qp : Kp;
    u16* dst = (tid < 128) ? qT : kT;
    const us8* sp = (const us8*)(src + (size_t)c * NP + (size_t)h * 128);
    us8 sv = sp[vj];
#pragma unroll
    for (int e = 0; e < 8; ++e) {
      int j = vj * 8 + e;
      int p = ((j & 7) << 4) | (j >> 3);
      dst[p * 8 + c] = sv[e];
    }
  }
  for (int i2 = tid; i2 < 1024; i2 += 256) {  // V: 8192 u16, b128 writes
    int c = i2 >> 4, vj = i2 & 15;
    const us8* vp = (const us8*)(Vp + (size_t)c * NP + (size_t)h * 128);
    us8 vv = vp[vj];
    *(us8*)&Vs[c * 136 + vj * 8] = vv;
  }
  __syncthreads();
  int lane = tid & 63, wvid = tid >> 6;  // wave owns rows [wvid*32, +32)
  int il = lane & 15, gq = lane >> 4;
  size_t sb = (size_t)(m * 4 + b) * NP;
  bf16* oBase = (mode ? OHT : OWb) + (size_t)((m * 4 + b) * 64) * NP +
                (size_t)h * 128;
#pragma unroll
  for (int sub = 0; sub < 2; ++sub) {
    int ib = wvid * 32 + sub * 16;
    int i = ib + il;                 // this lane's A-row (pixel index)
    int pi = ((i & 7) << 4) | (i >> 3);
    us8 qv = *(const us8*)&qT[pi * 8];
    float qr[8];
#pragma unroll
    for (int c = 0; c < 8; ++c) qr[c] = bfu(qv[c]);
    float scr[4][8];
    float mrow = -3.0e38f;
#pragma unroll
    for (int ks = 0; ks < 4; ++ks) {
#pragma unroll
      for (int e = 0; e < 8; ++e) {
        int j = ks * 32 + gq * 8 + e;
        int pj = ((j & 7) << 4) | (j >> 3);
        us8 kv = *(const us8*)&kT[pj * 8];
        float s = 0.f;
#pragma unroll
        for (int c = 0; c < 8; ++c) s = fmaf(qr[c], bfu(kv[c]), s);
        if (mode && j == i) s = -1.0e30f;   // diag mask (exp underflows to 0)
        scr[ks][e] = s;
        mrow = fmaxf(mrow, s);
      }
    }
    mrow = fmaxf(mrow, __shfl_xor(mrow, 16, 64));
    mrow = fmaxf(mrow, __shfl_xor(mrow, 32, 64));
    float l = 0.f;
    ss8 afr[4];
#pragma unroll
    for (int ks = 0; ks < 4; ++ks) {
      ss8 af;
#pragma unroll
      for (int e = 0; e < 8; ++e) {
        float ev = __expf(scr[ks][e] - mrow);
        l += ev;
        af[e] = (short)fbu(ev);
      }
      afr[ks] = af;
    }
    l += __shfl_xor(l, 16, 64);
    l += __shfl_xor(l, 32, 64);
    if (gq == 0) {
      if (mode == 0) {
        MWp[sb + (size_t)h * 128 + i] = mrow;
        LWp[sb + (size_t)h * 128 + i] = l;
      } else {  // store [h][w]-oriented: row i is the h coordinate
        MHp[sb + (size_t)i * 128 + h] = mrow;
        LHp[sb + (size_t)i * 128 + h] = l;
      }
    }
#pragma unroll
    for (int ct = 0; ct < 4; ++ct) {
      f32x4 acc = {0.f, 0.f, 0.f, 0.f};
#pragma unroll
      for (int ks = 0; ks < 4; ++ks) {
        ss8 bv = *(const ss8*)&Vs[(ct * 16 + il) * 136 + ks * 32 + gq * 8];
        acc = __builtin_amdgcn_mfma_f32_16x16x32_bf16(afr[ks], bv, acc, 0, 0, 0);
      }
      int cch = ct * 16 + il;        // D col = channel
      int i0 = ib + gq * 4;          // D rows = 4 consecutive pixels
      us4 ov;
#pragma unroll
      for (int r = 0; r < 4; ++r) ov[r] = fbu(acc[r]);
      *(us4*)(oBase + (size_t)cch * NP + i0) = ov;
    }
  }
}

// ---------------------------------------------------------------------------
// K6: fused dispatch: blocks [0,4096) = flash combine
// ACC = sum_m sc_m*(a_m*OW_m + b_m*OHT_m^T)/L_m ; blocks [4096,4160) =
// Gram-partial reduce + row softmax of (max-E) -> CATT.
// ---------------------------------------------------------------------------
__global__ __launch_bounds__(256) void k_merge_reduce(
    const bf16* __restrict__ OHT, const bf16* __restrict__ OWb,
    const float* __restrict__ MWp, const float* __restrict__ LWp,
    const float* __restrict__ MHp, const float* __restrict__ LHp,
    const float* __restrict__ HDR, float* __restrict__ ACC,
    const float* __restrict__ GP, float* __restrict__ CATT) {
  int tid = threadIdx.x;
  if (blockIdx.x < 4096) {
    int tileId = blockIdx.x & 15;
    int plane = blockIdx.x >> 4;      // 0..255 = b*64+c
    int b = plane >> 6;
    int th = tileId >> 2, tw = tileId & 3;
    __shared__ float t0[32][33], t1[32][33];
    int lx = tid & 31, ly = tid >> 5;
    const bf16* ip0 = OHT + (size_t)plane * NP;
    const bf16* ip1 = OHT + (size_t)(256 + plane) * NP;
    for (int i = 0; i < 32; i += 8) {
      size_t idx = (size_t)(th * 32 + ly + i) * 128 + tw * 32 + lx;
      t0[ly + i][lx] = bf2f(ip0[idx]);
      t1[ly + i][lx] = bf2f(ip1[idx]);
    }
    __syncthreads();
    float sc0 = HDR[1], sc1 = HDR[2];
    float* op = ACC + (size_t)plane * NP;
    const bf16* ow0 = OWb + (size_t)plane * NP;
    const bf16* ow1 = OWb + (size_t)(256 + plane) * NP;
    size_t s0 = (size_t)b * NP, s1 = (size_t)(4 + b) * NP;
    for (int i = 0; i < 32; i += 8) {
      int hh = tw * 32 + ly + i, ww = th * 32 + lx;
      size_t idx = (size_t)hh * 128 + ww;
      float mw0 = MWp[s0 + idx], mh0 = MHp[s0 + idx];
      float M0 = fmaxf(mw0, mh0);
      float ea0 = __expf(mw0 - M0), eb0 = __expf(mh0 - M0);
      float inv0 = 1.0f / (LWp[s0 + idx] * ea0 + LHp[s0 + idx] * eb0);
      float v0 = (ea0 * bf2f(ow0[idx]) + eb0 * t0[lx][ly + i]) * inv0;
      float mw1 = MWp[s1 + idx], mh1 = MHp[s1 + idx];
      float M1 = fmaxf(mw1, mh1);
      float ea1 = __expf(mw1 - M1), eb1 = __expf(mh1 - M1);
      float inv1 = 1.0f / (LWp[s1 + idx] * ea1 + LHp[s1 + idx] * eb1);
      float v1 = (ea1 * bf2f(ow1[idx]) + eb1 * t1[lx][ly + i]) * inv1;
      op[idx] = sc0 * v0 + sc1 * v1;
    }
  } else {
    int bid = blockIdx.x - 4096;
    int b = bid >> 4, rg = bid & 15;
    __shared__ float Es[256];
    int e = rg * 256 + tid;
    float s = 0.f;
    for (int k = 0; k < 128; ++k) s += GP[((size_t)b * 128 + k) * 4096 + e];
    Es[tid] = s;
    __syncthreads();
    int wvid = tid >> 6, ln = tid & 63;
    float v = Es[wvid * 64 + ln];
    float mn = v;
    for (int off = 32; off; off >>= 1) mn = fminf(mn, __shfl_xor(mn, off, 64));
    float ev = __expf(mn - v);
    float ssum = ev;
    for (int off = 32; off; off >>= 1) ssum += __shfl_xor(ssum, off, 64);
    CATT[((size_t)b * 64 + rg * 4 + wvid) * 64 + ln] = ev / ssum;
  }
}

// ---------------------------------------------------------------------------
// K7: out = (2+pg)*x + pg2*y + ACC + cg*(catt@y). In-place fp32 on d_out.
// ---------------------------------------------------------------------------
__global__ __launch_bounds__(256) void k_final(
    const float* __restrict__ x, const bf16* __restrict__ Y,
    const float* __restrict__ SCALE, const float* __restrict__ SHIFT,
    const float* __restrict__ CATT, const float* __restrict__ HDR,
    float* __restrict__ OUT) {
  __shared__ float attS[64 * 65], Ys[64 * 65];
  int tid = threadIdx.x;
  int b = blockIdx.x >> 8, tile = blockIdx.x & 255;
  int n0 = tile * 64;
  for (int i = tid; i < 4096; i += 256)
    attS[(i >> 6) * 65 + (i & 63)] = CATT[(size_t)b * 4096 + i];
  for (int i = tid; i < 4096; i += 256) {
    int d = i >> 6, px = i & 63;
    float v = fmaf(bf2f(Y[(size_t)(b * 64 + d) * NP + n0 + px]), SCALE[d], SHIFT[d]);
    Ys[d * 65 + px] = fmaxf(v, 0.f);
  }
  __syncthreads();
  int cg = tid >> 4, pgx = tid & 15;
  int c0 = cg * 4, p0 = pgx * 4;
  float acc[4][4];
#pragma unroll
  for (int i = 0; i < 4; ++i)
#pragma unroll
    for (int j = 0; j < 4; ++j) acc[i][j] = 0.f;
  for (int d = 0; d < 64; ++d) {
    float a[4], yv[4];
#pragma unroll
    for (int i = 0; i < 4; ++i) a[i] = attS[(c0 + i) * 65 + d];
#pragma unroll
    for (int j = 0; j < 4; ++j) yv[j] = Ys[d * 65 + p0 + j];
#pragma unroll
    for (int i = 0; i < 4; ++i)
#pragma unroll
      for (int j = 0; j < 4; ++j) acc[i][j] = fmaf(a[i], yv[j], acc[i][j]);
  }
  float c2pg = HDR[3], fpg2 = HDR[4], fcg = HDR[5];
#pragma unroll
  for (int i = 0; i < 4; ++i) {
    size_t base = (size_t)(b * 64 + c0 + i) * NP + n0 + p0;
#pragma unroll
    for (int j = 0; j < 4; ++j) {
      float yv = Ys[(c0 + i) * 65 + p0 + j];
      OUT[base + j] =
          c2pg * x[base + j] + fpg2 * yv + OUT[base + j] + fcg * acc[i][j];
    }
  }
}

// ---------------------------------------------------------------------------
extern "C" void kernel_launch(void* const* d_in, const int* in_sizes, int n_in,
                              void* d_out, int out_size, void* d_ws, size_t ws_size,
                              hipStream_t stream) {
  const float* x = (const float*)d_in[0];
  const float* fbp = (const float*)d_in[1];

  // ~92 MB of the 256 MiB workspace.
  char* base = (char*)d_ws;
  float* HDR = (float*)base;
  float* SCALE = HDR + 16;
  float* SHIFT = SCALE + 64;
  char* p = base + 4096;
  bf16* Y = (bf16*)p;    p += 8388608;   // [4][64][NP]
  bf16* QK = (bf16*)p;   p += 4194304;   // [m][q/k][4][8][NP] = 128 planes
  bf16* QKT = (bf16*)p;  p += 4194304;
  bf16* V = (bf16*)p;    p += 16777216;  // [m][4][64][NP] = 512 planes
  bf16* VT = (bf16*)p;   p += 16777216;
  float* MWp = (float*)p; p += 524288;   // [m][4][NP] raw w-dir max ([h][w])
  float* LWp = (float*)p; p += 524288;   // raw w-dir sumexp
  float* MHp = (float*)p; p += 524288;   // raw h-dir max ([h][w]-oriented)
  float* LHp = (float*)p; p += 524288;   // raw h-dir sumexp
  bf16* OHT = (bf16*)p;  p += 16777216;  // [m][4][64][NP] raw out_h [c][w][h]
  bf16* OWb = (bf16*)p;  p += 16777216;  // [m][4][64][NP] raw out_w bf16
  float* GP = (float*)p; p += 8388608;   // Gram partials
  float* CATT = (float*)p; p += 1048576;
  float* ACC = (float*)d_out;
  float* PS = (float*)QK;  // stats partials (512 KB), QK unused until conv

  // 1: pool+conv+stats-partials
  k_pool_conv<<<1024, 256, 0, stream>>>(fbp, (const float*)d_in[2],
                                        (const float*)d_in[3], Y, PS);
  // 2: stats reduce + BN params + header
  k_stats_p2<<<1, 256, 0, stream>>>(PS, (const float*)d_in[4],
                                    (const float*)d_in[5], SCALE, SHIFT,
                                    (const float*)d_in[12], (const float*)d_in[19],
                                    (const float*)d_in[20], (const float*)d_in[21],
                                    (const float*)d_in[22], HDR);
  // 3: QKV conv (both modules) + Gram partials in one dispatch
  k_conv_gram<<<1536, 256, 0, stream>>>(
      x, Y, SCALE, SHIFT,
      (const float*)d_in[6], (const float*)d_in[7], (const float*)d_in[8],
      (const float*)d_in[9], (const float*)d_in[10], (const float*)d_in[11],
      (const float*)d_in[13], (const float*)d_in[14], (const float*)d_in[15],
      (const float*)d_in[16], (const float*)d_in[17], (const float*)d_in[18],
      QK, V, GP);
  // 4: transpose QK (128 planes) + V (512 planes)
  k_transpose2<<<10240, 256, 0, stream>>>((const u16*)QK, (u16*)QKT,
                                          (const u16*)V, (u16*)VT, 128);
  // 5: flash-style attention: stats + unnormalized outputs (bf16)
  k_av<<<2048, 256, 0, stream>>>(QK, QKT, V, VT, MWp, LWp, MHp, LHp, OWb, OHT);
  // 6: exact combine -> ACC, plus Gram reduce -> CATT
  k_merge_reduce<<<4160, 256, 0, stream>>>(OHT, OWb, MWp, LWp, MHp, LHp, HDR,
                                           ACC, GP, CATT);
  // 7: final residual + CAM
  k_final<<<1024, 256, 0, stream>>>(x, Y, SCALE, SHIFT, CATT, HDR,
                                    (float*)d_out);
}

// Round 11
// 265.447 us; speedup vs baseline: 1.4467x; 1.4467x over previous
//
#include <hip/hip_runtime.h>
#include <hip/hip_bf16.h>

#define NP 16384   // H*W
#define NB 4

typedef __hip_bfloat16 bf16;
typedef unsigned short u16;
typedef unsigned short us8 __attribute__((ext_vector_type(8)));
typedef unsigned short us4 __attribute__((ext_vector_type(4)));
typedef short ss8 __attribute__((ext_vector_type(8)));
typedef float f32x4 __attribute__((ext_vector_type(4)));
__device__ __forceinline__ float bf2f(const bf16 v) { return __bfloat162float(v); }
__device__ __forceinline__ bf16 f2bf(float v) { return __float2bfloat16(v); }
__device__ __forceinline__ float bfu(u16 h) {
  return __uint_as_float(((unsigned)h) << 16);
}
__device__ __forceinline__ u16 fbu(float v) {
  bf16 b = f2bf(v);
  return *(u16*)&b;
}

// Inputs/outputs fp32 (reference dtype). Internal tensors bf16, math fp32.
// 7-dispatch pipeline: pool_conv(+stats partials) -> stats_p2(64 blk) ->
// conv+gram -> transpose -> av (flash) -> merge+gram_reduce -> final.

// ---------------------------------------------------------------------------
// K1: maxpool2x2(fb) + conv1x1 on MFMA + BN-stats partials. 1024 blocks =
// b(4) x 64-px tile(256). Stats reduced from fp32 acc (pre-rounding):
// per-oc sum/sumsq via shfl_xor(16/32) + 2KB LDS -> PS[blk][128].
// ---------------------------------------------------------------------------
__global__ __launch_bounds__(256, 4) void k_pool_conv(
    const float* __restrict__ fb, const float* __restrict__ wconv,
    const float* __restrict__ bconv, bf16* __restrict__ Y,
    float* __restrict__ PS) {
  __shared__ __align__(16) u16 Xs[64 * 64];               // [px][c], swizzled
  __shared__ __align__(16) u16 wHi[64 * 64], wLo[64 * 64];  // [oc][c], swz
  __shared__ float bS[64];
  __shared__ float redS[256], redSS[256];   // [wave][oc]
  int tid = threadIdx.x;
  int b = blockIdx.x >> 8, tile = blockIdx.x & 255;
  int n0 = tile * 64;
  int h = n0 >> 7, w0 = n0 & 127;
  for (int i = tid; i < 4096; i += 256) {
    int oc = i >> 6;
    float wv = wconv[i];
    u16 hb = fbu(wv);
    u16 lb = fbu(wv - bfu(hb));
    int idx = i ^ ((oc & 7) << 3);
    wHi[idx] = hb;
    wLo[idx] = lb;
  }
  if (tid < 64) bS[tid] = bconv[tid];
  for (int i2 = tid; i2 < 2048; i2 += 256) {
    int c = i2 >> 5, pp = i2 & 31;
    const float* r0 =
        fb + ((size_t)((b * 64 + c) * 256 + 2 * h)) * 256 + 2 * w0 + 4 * pp;
    float4 v0 = *(const float4*)r0;
    float4 v1 = *(const float4*)(r0 + 256);
    int px = 2 * pp;
    float a0 = fmaxf(fmaxf(v0.x, v0.y), fmaxf(v1.x, v1.y));
    float a1 = fmaxf(fmaxf(v0.z, v0.w), fmaxf(v1.z, v1.w));
    Xs[(px * 64 + c) ^ ((((px & 7) ^ ((px >> 3) & 7))) << 3)] = fbu(a0);
    px++;
    Xs[(px * 64 + c) ^ ((((px & 7) ^ ((px >> 3) & 7))) << 3)] = fbu(a1);
  }
  __syncthreads();
  int lane = tid & 63, wvid = tid >> 6;
  int il = lane & 15, gq = lane >> 4;
  int pxb = wvid * 16;               // wave owns 16 px
  ss8 afr[2];
#pragma unroll
  for (int ks = 0; ks < 2; ++ks) {
    int px = pxb + il;
    int idx =
        (px * 64 + ks * 32 + gq * 8) ^ ((((px & 7) ^ ((px >> 3) & 7))) << 3);
    afr[ks] = *(const ss8*)&Xs[idx];
  }
#pragma unroll
  for (int oct = 0; oct < 4; ++oct) {
    int oc = oct * 16 + il;          // B-col = out-channel
    ss8 wh[2], wl[2];
#pragma unroll
    for (int ks = 0; ks < 2; ++ks) {
      int idx = (oc * 64 + ks * 32 + gq * 8) ^ ((oc & 7) << 3);
      wh[ks] = *(const ss8*)&wHi[idx];
      wl[ks] = *(const ss8*)&wLo[idx];
    }
    float bv = bS[oc];
    f32x4 acc = {bv, bv, bv, bv};
#pragma unroll
    for (int ks = 0; ks < 2; ++ks) {
      acc = __builtin_amdgcn_mfma_f32_16x16x32_bf16(afr[ks], wh[ks], acc, 0, 0, 0);
      acc = __builtin_amdgcn_mfma_f32_16x16x32_bf16(afr[ks], wl[ks], acc, 0, 0, 0);
    }
    int px0 = pxb + gq * 4;          // D rows = 4 consecutive px
    us4 ov;
#pragma unroll
    for (int r = 0; r < 4; ++r) ov[r] = fbu(acc[r]);
    *(us4*)(Y + (size_t)(b * 64 + oc) * NP + n0 + px0) = ov;
    // BN stats partials (fp32, pre-rounding)
    float s_oc = (acc[0] + acc[1]) + (acc[2] + acc[3]);
    float ss_oc = fmaf(acc[0], acc[0],
                  fmaf(acc[1], acc[1], fmaf(acc[2], acc[2], acc[3] * acc[3])));
    s_oc += __shfl_xor(s_oc, 16, 64);
    s_oc += __shfl_xor(s_oc, 32, 64);
    ss_oc += __shfl_xor(ss_oc, 16, 64);
    ss_oc += __shfl_xor(ss_oc, 32, 64);
    if (gq == 0) { redS[wvid * 64 + oc] = s_oc; redSS[wvid * 64 + oc] = ss_oc; }
  }
  __syncthreads();
  if (tid < 128) {
    int st = tid >> 6, oc = tid & 63;
    const float* rr = st ? redSS : redS;
    PS[(size_t)blockIdx.x * 128 + tid] =
        (rr[oc] + rr[64 + oc]) + (rr[128 + oc] + rr[192 + oc]);
  }
}

// ---------------------------------------------------------------------------
// K2: reduce 1024x128 stats partials. 64 blocks = one per channel; each
// block's 256 threads sweep the 1024 partials (4 strided loads x 2 arrays),
// wave-shuffle + LDS reduce. (R9's grid=1 version was a 122 us serial
// bottleneck -- one CU pulling 512 KB.)
// ---------------------------------------------------------------------------
__global__ __launch_bounds__(256) void k_stats_p2(
    const float* __restrict__ PS, const float* __restrict__ bng,
    const float* __restrict__ bnb, float* __restrict__ SCALE,
    float* __restrict__ SHIFT, const float* xg, const float* fg,
    const float* pg, const float* pg2, const float* cg,
    float* __restrict__ HDR) {
  int o = blockIdx.x;   // channel
  int t = threadIdx.x;
  float s = 0.f, ss = 0.f;
#pragma unroll
  for (int k = 0; k < 4; ++k) {
    size_t blk = t + 256 * k;
    s += PS[blk * 128 + o];
    ss += PS[blk * 128 + 64 + o];
  }
  for (int off = 32; off; off >>= 1) {
    s += __shfl_down(s, off, 64);
    ss += __shfl_down(ss, off, 64);
  }
  __shared__ float sh[8];
  int wv = t >> 6, ln = t & 63;
  if (ln == 0) { sh[wv] = s; sh[4 + wv] = ss; }
  __syncthreads();
  if (t == 0) {
    float ssum = (sh[0] + sh[1]) + (sh[2] + sh[3]);
    float sqs = (sh[4] + sh[5]) + (sh[6] + sh[7]);
    const float inv = 1.0f / (NB * NP);
    float mu = ssum * inv;
    float var = sqs * inv - mu * mu;
    float r = rsqrtf(var + 1e-5f);
    float sc = r * bng[o];
    SCALE[o] = sc;
    SHIFT[o] = bnb[o] - mu * sc;
    if (o == 0) {
      float vpg = pg[0];
      HDR[1] = vpg * xg[0];
      HDR[2] = pg2[0] * fg[0];
      HDR[3] = 2.0f + vpg;
      HDR[4] = pg2[0];
      HDR[5] = cg[0];
    }
  }
}

// ---------------------------------------------------------------------------
// K3: fused dispatch: blocks [0,1024) = QKV conv1x1 on MFMA (both modules,
// weights hi+lo bf16); blocks [1024,1536) = Gram partials of y=BN(Y).
// Shared memory unioned via one char buffer (37.2 KB).
// ---------------------------------------------------------------------------
__global__ __launch_bounds__(256, 4) void k_conv_gram(
    const float* __restrict__ xin, const bf16* __restrict__ Yin,
    const float* __restrict__ SCALE, const float* __restrict__ SHIFT,
    const float* __restrict__ qw0, const float* __restrict__ qb0,
    const float* __restrict__ kw0, const float* __restrict__ kb0,
    const float* __restrict__ vw0, const float* __restrict__ vb0,
    const float* __restrict__ qw1, const float* __restrict__ qb1,
    const float* __restrict__ kw1, const float* __restrict__ kb1,
    const float* __restrict__ vw1, const float* __restrict__ vb1,
    bf16* __restrict__ QK, bf16* __restrict__ V, float* __restrict__ GP) {
  __shared__ __align__(16) char SMEM[37248];
  int tid = threadIdx.x;
  if (blockIdx.x < 1024) {
    u16* Xs = (u16*)SMEM;                    // 16384 B [px][c], swizzled
    u16* wHi = (u16*)(SMEM + 16384);         // 10240 B [oc][c], swz
    u16* wLo = (u16*)(SMEM + 26624);         // 10240 B
    float* bS = (float*)(SMEM + 36864);      // 320 B
    int m = blockIdx.x >> 9;
    int b = (blockIdx.x >> 7) & 3;
    int tile = blockIdx.x & 127;
    int n0 = tile * 128;
    const float* qw = m ? qw1 : qw0;
    const float* qb = m ? qb1 : qb0;
    const float* kw = m ? kw1 : kw0;
    const float* kb = m ? kb1 : kb0;
    const float* vw = m ? vw1 : vw0;
    const float* vb = m ? vb1 : vb0;
    for (int i = tid; i < 5120; i += 256) {
      int oc = i >> 6, c = i & 63;
      float w;
      if (oc < 8) w = qw[oc * 64 + c];
      else if (oc < 16) w = kw[(oc - 8) * 64 + c];
      else w = vw[(oc - 16) * 64 + c];
      u16 hb = fbu(w);
      u16 lb = fbu(w - bfu(hb));
      int idx = (oc * 64 + c) ^ ((oc & 7) << 3);
      wHi[idx] = hb;
      wLo[idx] = lb;
    }
    if (tid < 80)
      bS[tid] = (tid < 8) ? qb[tid] : (tid < 16) ? kb[tid - 8] : vb[tid - 16];
    if (m) {
      for (int i2 = tid; i2 < 1024; i2 += 256) {
        int c = i2 >> 4, vj = i2 & 15;
        us8 v = *(const us8*)(Yin + (size_t)(b * 64 + c) * NP + n0 + vj * 8);
        float sc = SCALE[c], sh = SHIFT[c];
#pragma unroll
        for (int e = 0; e < 8; ++e) {
          int px = vj * 8 + e;
          float f = fmaxf(fmaf(bfu(v[e]), sc, sh), 0.f);
          Xs[(px * 64 + c) ^ ((((px & 7) ^ ((px >> 3) & 7))) << 3)] = fbu(f);
        }
      }
    } else {
      for (int i2 = tid; i2 < 2048; i2 += 256) {
        int c = i2 >> 5, vj = i2 & 31;
        float4 v = *(const float4*)(xin + (size_t)(b * 64 + c) * NP + n0 + vj * 4);
        float vv[4] = {v.x, v.y, v.z, v.w};
#pragma unroll
        for (int r = 0; r < 4; ++r) {
          int px = vj * 4 + r;
          Xs[(px * 64 + c) ^ ((((px & 7) ^ ((px >> 3) & 7))) << 3)] = fbu(vv[r]);
        }
      }
    }
    __syncthreads();
    int lane = tid & 63, wvid = tid >> 6;
    int il = lane & 15, gq = lane >> 4;
    int pxb = wvid * 32;
    ss8 afr[2][2];
#pragma unroll
    for (int sub = 0; sub < 2; ++sub)
#pragma unroll
      for (int ks = 0; ks < 2; ++ks) {
        int px = pxb + sub * 16 + il;
        int idx =
            (px * 64 + ks * 32 + gq * 8) ^ ((((px & 7) ^ ((px >> 3) & 7))) << 3);
        afr[sub][ks] = *(const ss8*)&Xs[idx];
      }
#pragma unroll
    for (int oct = 0; oct < 5; ++oct) {
      int oc = oct * 16 + il;   // B-col = out-channel
      ss8 wh[2], wl[2];
#pragma unroll
      for (int ks = 0; ks < 2; ++ks) {
        int idx = (oc * 64 + ks * 32 + gq * 8) ^ ((oc & 7) << 3);
        wh[ks] = *(const ss8*)&wHi[idx];
        wl[ks] = *(const ss8*)&wLo[idx];
      }
      float bv = bS[oc];
      bf16* dst;
      size_t basep;
      if (oc < 8) { dst = QK; basep = (size_t)(((m * 2 + 0) * 4 + b) * 8 + oc) * NP; }
      else if (oc < 16) { dst = QK; basep = (size_t)(((m * 2 + 1) * 4 + b) * 8 + (oc - 8)) * NP; }
      else { dst = V; basep = (size_t)((m * 4 + b) * 64 + (oc - 16)) * NP; }
#pragma unroll
      for (int sub = 0; sub < 2; ++sub) {
        f32x4 acc = {bv, bv, bv, bv};
#pragma unroll
        for (int ks = 0; ks < 2; ++ks) {
          acc = __builtin_amdgcn_mfma_f32_16x16x32_bf16(afr[sub][ks], wh[ks], acc, 0, 0, 0);
          acc = __builtin_amdgcn_mfma_f32_16x16x32_bf16(afr[sub][ks], wl[ks], acc, 0, 0, 0);
        }
        int px0 = pxb + sub * 16 + gq * 4;   // D rows = 4 consecutive px
        us4 ov;
#pragma unroll
        for (int r = 0; r < 4; ++r) ov[r] = fbu(acc[r]);
        *(us4*)(dst + basep + n0 + px0) = ov;
      }
    }
  } else {
    // ---- Gram partials: bid = b x ch x t ----
    float* fs = (float*)SMEM;   // 64*129 floats = 33024 B
    int bid = blockIdx.x - 1024;
    int b = bid >> 7, ch = (bid >> 2) & 31, t = bid & 3;
    int cg = tid >> 4, dg = tid & 15;
    float acc[4][4];
#pragma unroll
    for (int i = 0; i < 4; ++i)
#pragma unroll
      for (int jx = 0; jx < 4; ++jx) acc[i][jx] = 0.f;
    const bf16* yb = Yin + (size_t)b * 64 * NP + ch * 512;
    for (int idx = tid; idx < 8192; idx += 256) {
      int c = idx >> 7, j = idx & 127;
      float v = fmaf(bf2f(yb[(size_t)c * NP + t * 128 + j]), SCALE[c], SHIFT[c]);
      fs[c * 129 + j] = fmaxf(v, 0.f);
    }
    __syncthreads();
    for (int j = 0; j < 128; ++j) {
      float a[4], d[4];
#pragma unroll
      for (int i = 0; i < 4; ++i) a[i] = fs[(cg * 4 + i) * 129 + j];
#pragma unroll
      for (int i = 0; i < 4; ++i) d[i] = fs[(dg * 4 + i) * 129 + j];
#pragma unroll
      for (int i = 0; i < 4; ++i)
#pragma unroll
        for (int jx = 0; jx < 4; ++jx) acc[i][jx] = fmaf(a[i], d[jx], acc[i][jx]);
    }
    float* gp = GP + ((size_t)(b * 128) + ch * 4 + t) * 4096;
#pragma unroll
    for (int i = 0; i < 4; ++i)
#pragma unroll
      for (int jx = 0; jx < 4; ++jx)
        gp[(cg * 4 + i) * 64 + dg * 4 + jx] = acc[i][jx];
  }
}

// ---------------------------------------------------------------------------
// K4: 128x128 bf16 plane transpose over two tensor pairs in one dispatch.
// ---------------------------------------------------------------------------
__global__ __launch_bounds__(256) void k_transpose2(
    const u16* __restrict__ inA, u16* __restrict__ outA,
    const u16* __restrict__ inB, u16* __restrict__ outB, int nA) {
  int tileId = blockIdx.x & 15;
  int plane = blockIdx.x >> 4;
  const u16* ip;
  u16* op;
  if (plane < nA) {
    ip = inA + (size_t)plane * NP;
    op = outA + (size_t)plane * NP;
  } else {
    ip = inB + (size_t)(plane - nA) * NP;
    op = outB + (size_t)(plane - nA) * NP;
  }
  int th = tileId >> 2, tw = tileId & 3;
  __shared__ u16 t[32][33];
  int lx = threadIdx.x & 31, ly = threadIdx.x >> 5;
  for (int i = 0; i < 32; i += 8)
    t[ly + i][lx] = ip[(size_t)(th * 32 + ly + i) * 128 + tw * 32 + lx];
  __syncthreads();
  for (int i = 0; i < 32; i += 8)
    op[(size_t)(tw * 32 + ly + i) * 128 + th * 32 + lx] = t[lx][ly + i];
}

// ---------------------------------------------------------------------------
// K5: out_w + out_h, both modules, on MFMA, flash-style. 2048 blocks =
// (b,h) x mode x m; 256 thr. Both outputs bf16 (OWb and OHT).
// ---------------------------------------------------------------------------
__global__ __launch_bounds__(256, 4) void k_av(
    const bf16* __restrict__ QK, const bf16* __restrict__ QKT,
    const bf16* __restrict__ V, const bf16* __restrict__ VT,
    float* __restrict__ MWp, float* __restrict__ LWp,
    float* __restrict__ MHp, float* __restrict__ LHp,
    bf16* __restrict__ OWb, bf16* __restrict__ OHT) {
  int blk = blockIdx.x;
  int m = blk & 1, mode = (blk >> 1) & 1;
  int bid = blk >> 2;
  int b = bid >> 7, h = bid & 127;
  const bf16* qkbase = mode ? QKT : QK;
  const bf16* Qp = qkbase + (size_t)(((m * 2 + 0) * 4 + b) * 8) * NP;
  const bf16* Kp = qkbase + (size_t)(((m * 2 + 1) * 4 + b) * 8) * NP;
  const bf16* Vp = (mode ? VT : V) + (size_t)((m * 4 + b) * 64) * NP;
  __shared__ __align__(16) u16 qT[128 * 8];    // [p(j)][c]
  __shared__ __align__(16) u16 kT[128 * 8];    // [p(j)][c]
  __shared__ __align__(16) u16 Vs[64 * 136];   // [c][j], pad 136
  int tid = threadIdx.x;
  {  // q (tid<128) / k (tid>=128): 1024 u16 each, one us8 load per thread
    int c = (tid >> 4) & 7, vj = tid & 15;
    const bf16* src = (tid < 128) ? Qp : Kp;
    u16* dst = (tid < 128) ? qT : kT;
    const us8* sp = (const us8*)(src + (size_t)c * NP + (size_t)h * 128);
    us8 sv = sp[vj];
#pragma unroll
    for (int e = 0; e < 8; ++e) {
      int j = vj * 8 + e;
      int p = ((j & 7) << 4) | (j >> 3);
      dst[p * 8 + c] = sv[e];
    }
  }
  for (int i2 = tid; i2 < 1024; i2 += 256) {  // V: 8192 u16, b128 writes
    int c = i2 >> 4, vj = i2 & 15;
    const us8* vp = (const us8*)(Vp + (size_t)c * NP + (size_t)h * 128);
    us8 vv = vp[vj];
    *(us8*)&Vs[c * 136 + vj * 8] = vv;
  }
  __syncthreads();
  int lane = tid & 63, wvid = tid >> 6;  // wave owns rows [wvid*32, +32)
  int il = lane & 15, gq = lane >> 4;
  size_t sb = (size_t)(m * 4 + b) * NP;
  bf16* oBase = (mode ? OHT : OWb) + (size_t)((m * 4 + b) * 64) * NP +
                (size_t)h * 128;
#pragma unroll
  for (int sub = 0; sub < 2; ++sub) {
    int ib = wvid * 32 + sub * 16;
    int i = ib + il;                 // this lane's A-row (pixel index)
    int pi = ((i & 7) << 4) | (i >> 3);
    us8 qv = *(const us8*)&qT[pi * 8];
    float qr[8];
#pragma unroll
    for (int c = 0; c < 8; ++c) qr[c] = bfu(qv[c]);
    float scr[4][8];
    float mrow = -3.0e38f;
#pragma unroll
    for (int ks = 0; ks < 4; ++ks) {
#pragma unroll
      for (int e = 0; e < 8; ++e) {
        int j = ks * 32 + gq * 8 + e;
        int pj = ((j & 7) << 4) | (j >> 3);
        us8 kv = *(const us8*)&kT[pj * 8];
        float s = 0.f;
#pragma unroll
        for (int c = 0; c < 8; ++c) s = fmaf(qr[c], bfu(kv[c]), s);
        if (mode && j == i) s = -1.0e30f;   // diag mask (exp underflows to 0)
        scr[ks][e] = s;
        mrow = fmaxf(mrow, s);
      }
    }
    mrow = fmaxf(mrow, __shfl_xor(mrow, 16, 64));
    mrow = fmaxf(mrow, __shfl_xor(mrow, 32, 64));
    float l = 0.f;
    ss8 afr[4];
#pragma unroll
    for (int ks = 0; ks < 4; ++ks) {
      ss8 af;
#pragma unroll
      for (int e = 0; e < 8; ++e) {
        float ev = __expf(scr[ks][e] - mrow);
        l += ev;
        af[e] = (short)fbu(ev);
      }
      afr[ks] = af;
    }
    l += __shfl_xor(l, 16, 64);
    l += __shfl_xor(l, 32, 64);
    if (gq == 0) {
      if (mode == 0) {
        MWp[sb + (size_t)h * 128 + i] = mrow;
        LWp[sb + (size_t)h * 128 + i] = l;
      } else {  // store [h][w]-oriented: row i is the h coordinate
        MHp[sb + (size_t)i * 128 + h] = mrow;
        LHp[sb + (size_t)i * 128 + h] = l;
      }
    }
#pragma unroll
    for (int ct = 0; ct < 4; ++ct) {
      f32x4 acc = {0.f, 0.f, 0.f, 0.f};
#pragma unroll
      for (int ks = 0; ks < 4; ++ks) {
        ss8 bv = *(const ss8*)&Vs[(ct * 16 + il) * 136 + ks * 32 + gq * 8];
        acc = __builtin_amdgcn_mfma_f32_16x16x32_bf16(afr[ks], bv, acc, 0, 0, 0);
      }
      int cch = ct * 16 + il;        // D col = channel
      int i0 = ib + gq * 4;          // D rows = 4 consecutive pixels
      us4 ov;
#pragma unroll
      for (int r = 0; r < 4; ++r) ov[r] = fbu(acc[r]);
      *(us4*)(oBase + (size_t)cch * NP + i0) = ov;
    }
  }
}

// ---------------------------------------------------------------------------
// K6: fused dispatch: blocks [0,4096) = flash combine
// ACC = sum_m sc_m*(a_m*OW_m + b_m*OHT_m^T)/L_m ; blocks [4096,4160) =
// Gram-partial reduce + row softmax of (max-E) -> CATT.
// ---------------------------------------------------------------------------
__global__ __launch_bounds__(256) void k_merge_reduce(
    const bf16* __restrict__ OHT, const bf16* __restrict__ OWb,
    const float* __restrict__ MWp, const float* __restrict__ LWp,
    const float* __restrict__ MHp, const float* __restrict__ LHp,
    const float* __restrict__ HDR, float* __restrict__ ACC,
    const float* __restrict__ GP, float* __restrict__ CATT) {
  int tid = threadIdx.x;
  if (blockIdx.x < 4096) {
    int tileId = blockIdx.x & 15;
    int plane = blockIdx.x >> 4;      // 0..255 = b*64+c
    int b = plane >> 6;
    int th = tileId >> 2, tw = tileId & 3;
    __shared__ float t0[32][33], t1[32][33];
    int lx = tid & 31, ly = tid >> 5;
    const bf16* ip0 = OHT + (size_t)plane * NP;
    const bf16* ip1 = OHT + (size_t)(256 + plane) * NP;
    for (int i = 0; i < 32; i += 8) {
      size_t idx = (size_t)(th * 32 + ly + i) * 128 + tw * 32 + lx;
      t0[ly + i][lx] = bf2f(ip0[idx]);
      t1[ly + i][lx] = bf2f(ip1[idx]);
    }
    __syncthreads();
    float sc0 = HDR[1], sc1 = HDR[2];
    float* op = ACC + (size_t)plane * NP;
    const bf16* ow0 = OWb + (size_t)plane * NP;
    const bf16* ow1 = OWb + (size_t)(256 + plane) * NP;
    size_t s0 = (size_t)b * NP, s1 = (size_t)(4 + b) * NP;
    for (int i = 0; i < 32; i += 8) {
      int hh = tw * 32 + ly + i, ww = th * 32 + lx;
      size_t idx = (size_t)hh * 128 + ww;
      float mw0 = MWp[s0 + idx], mh0 = MHp[s0 + idx];
      float M0 = fmaxf(mw0, mh0);
      float ea0 = __expf(mw0 - M0), eb0 = __expf(mh0 - M0);
      float inv0 = 1.0f / (LWp[s0 + idx] * ea0 + LHp[s0 + idx] * eb0);
      float v0 = (ea0 * bf2f(ow0[idx]) + eb0 * t0[lx][ly + i]) * inv0;
      float mw1 = MWp[s1 + idx], mh1 = MHp[s1 + idx];
      float M1 = fmaxf(mw1, mh1);
      float ea1 = __expf(mw1 - M1), eb1 = __expf(mh1 - M1);
      float inv1 = 1.0f / (LWp[s1 + idx] * ea1 + LHp[s1 + idx] * eb1);
      float v1 = (ea1 * bf2f(ow1[idx]) + eb1 * t1[lx][ly + i]) * inv1;
      op[idx] = sc0 * v0 + sc1 * v1;
    }
  } else {
    int bid = blockIdx.x - 4096;
    int b = bid >> 4, rg = bid & 15;
    __shared__ float Es[256];
    int e = rg * 256 + tid;
    float s = 0.f;
    for (int k = 0; k < 128; ++k) s += GP[((size_t)b * 128 + k) * 4096 + e];
    Es[tid] = s;
    __syncthreads();
    int wvid = tid >> 6, ln = tid & 63;
    float v = Es[wvid * 64 + ln];
    float mn = v;
    for (int off = 32; off; off >>= 1) mn = fminf(mn, __shfl_xor(mn, off, 64));
    float ev = __expf(mn - v);
    float ssum = ev;
    for (int off = 32; off; off >>= 1) ssum += __shfl_xor(ssum, off, 64);
    CATT[((size_t)b * 64 + rg * 4 + wvid) * 64 + ln] = ev / ssum;
  }
}

// ---------------------------------------------------------------------------
// K7: out = (2+pg)*x + pg2*y + ACC + cg*(catt@y). In-place fp32 on d_out.
// ---------------------------------------------------------------------------
__global__ __launch_bounds__(256) void k_final(
    const float* __restrict__ x, const bf16* __restrict__ Y,
    const float* __restrict__ SCALE, const float* __restrict__ SHIFT,
    const float* __restrict__ CATT, const float* __restrict__ HDR,
    float* __restrict__ OUT) {
  __shared__ float attS[64 * 65], Ys[64 * 65];
  int tid = threadIdx.x;
  int b = blockIdx.x >> 8, tile = blockIdx.x & 255;
  int n0 = tile * 64;
  for (int i = tid; i < 4096; i += 256)
    attS[(i >> 6) * 65 + (i & 63)] = CATT[(size_t)b * 4096 + i];
  for (int i = tid; i < 4096; i += 256) {
    int d = i >> 6, px = i & 63;
    float v = fmaf(bf2f(Y[(size_t)(b * 64 + d) * NP + n0 + px]), SCALE[d], SHIFT[d]);
    Ys[d * 65 + px] = fmaxf(v, 0.f);
  }
  __syncthreads();
  int cg = tid >> 4, pgx = tid & 15;
  int c0 = cg * 4, p0 = pgx * 4;
  float acc[4][4];
#pragma unroll
  for (int i = 0; i < 4; ++i)
#pragma unroll
    for (int j = 0; j < 4; ++j) acc[i][j] = 0.f;
  for (int d = 0; d < 64; ++d) {
    float a[4], yv[4];
#pragma unroll
    for (int i = 0; i < 4; ++i) a[i] = attS[(c0 + i) * 65 + d];
#pragma unroll
    for (int j = 0; j < 4; ++j) yv[j] = Ys[d * 65 + p0 + j];
#pragma unroll
    for (int i = 0; i < 4; ++i)
#pragma unroll
      for (int j = 0; j < 4; ++j) acc[i][j] = fmaf(a[i], yv[j], acc[i][j]);
  }
  float c2pg = HDR[3], fpg2 = HDR[4], fcg = HDR[5];
#pragma unroll
  for (int i = 0; i < 4; ++i) {
    size_t base = (size_t)(b * 64 + c0 + i) * NP + n0 + p0;
#pragma unroll
    for (int j = 0; j < 4; ++j) {
      float yv = Ys[(c0 + i) * 65 + p0 + j];
      OUT[base + j] =
          c2pg * x[base + j] + fpg2 * yv + OUT[base + j] + fcg * acc[i][j];
    }
  }
}

// ---------------------------------------------------------------------------
extern "C" void kernel_launch(void* const* d_in, const int* in_sizes, int n_in,
                              void* d_out, int out_size, void* d_ws, size_t ws_size,
                              hipStream_t stream) {
  const float* x = (const float*)d_in[0];
  const float* fbp = (const float*)d_in[1];

  // ~92 MB of the 256 MiB workspace.
  char* base = (char*)d_ws;
  float* HDR = (float*)base;
  float* SCALE = HDR + 16;
  float* SHIFT = SCALE + 64;
  char* p = base + 4096;
  bf16* Y = (bf16*)p;    p += 8388608;   // [4][64][NP]
  bf16* QK = (bf16*)p;   p += 4194304;   // [m][q/k][4][8][NP] = 128 planes
  bf16* QKT = (bf16*)p;  p += 4194304;
  bf16* V = (bf16*)p;    p += 16777216;  // [m][4][64][NP] = 512 planes
  bf16* VT = (bf16*)p;   p += 16777216;
  float* MWp = (float*)p; p += 524288;   // [m][4][NP] raw w-dir max ([h][w])
  float* LWp = (float*)p; p += 524288;   // raw w-dir sumexp
  float* MHp = (float*)p; p += 524288;   // raw h-dir max ([h][w]-oriented)
  float* LHp = (float*)p; p += 524288;   // raw h-dir sumexp
  bf16* OHT = (bf16*)p;  p += 16777216;  // [m][4][64][NP] raw out_h [c][w][h]
  bf16* OWb = (bf16*)p;  p += 16777216;  // [m][4][64][NP] raw out_w bf16
  float* GP = (float*)p; p += 8388608;   // Gram partials
  float* CATT = (float*)p; p += 1048576;
  float* ACC = (float*)d_out;
  float* PS = (float*)QK;  // stats partials (512 KB), QK unused until conv

  // 1: pool+conv+stats-partials
  k_pool_conv<<<1024, 256, 0, stream>>>(fbp, (const float*)d_in[2],
                                        (const float*)d_in[3], Y, PS);
  // 2: stats reduce + BN params + header (64 blocks = 1/channel)
  k_stats_p2<<<64, 256, 0, stream>>>(PS, (const float*)d_in[4],
                                     (const float*)d_in[5], SCALE, SHIFT,
                                     (const float*)d_in[12], (const float*)d_in[19],
                                     (const float*)d_in[20], (const float*)d_in[21],
                                     (const float*)d_in[22], HDR);
  // 3: QKV conv (both modules) + Gram partials in one dispatch
  k_conv_gram<<<1536, 256, 0, stream>>>(
      x, Y, SCALE, SHIFT,
      (const float*)d_in[6], (const float*)d_in[7], (const float*)d_in[8],
      (const float*)d_in[9], (const float*)d_in[10], (const float*)d_in[11],
      (const float*)d_in[13], (const float*)d_in[14], (const float*)d_in[15],
      (const float*)d_in[16], (const float*)d_in[17], (const float*)d_in[18],
      QK, V, GP);
  // 4: transpose QK (128 planes) + V (512 planes)
  k_transpose2<<<10240, 256, 0, stream>>>((const u16*)QK, (u16*)QKT,
                                          (const u16*)V, (u16*)VT, 128);
  // 5: flash-style attention: stats + unnormalized outputs (bf16)
  k_av<<<2048, 256, 0, stream>>>(QK, QKT, V, VT, MWp, LWp, MHp, LHp, OWb, OHT);
  // 6: exact combine -> ACC, plus Gram reduce -> CATT
  k_merge_reduce<<<4160, 256, 0, stream>>>(OHT, OWb, MWp, LWp, MHp, LHp, HDR,
                                           ACC, GP, CATT);
  // 7: final residual + CAM
  k_final<<<1024, 256, 0, stream>>>(x, Y, SCALE, SHIFT, CATT, HDR,
                                    (float*)d_out);
}